// Round 1
// 168.354 us; speedup vs baseline: 1.0920x; 1.0920x over previous
//
#include <hip/hip_runtime.h>
#include <hip/hip_bf16.h>

#define S_LEN 4096
#define HID   768
#define NH    12
#define HD    64

typedef __attribute__((ext_vector_type(8))) __bf16 bf16x8;
typedef __attribute__((ext_vector_type(4))) float  f32x4;

// round-to-nearest-even fp32 -> bf16
__device__ __forceinline__ unsigned short f2bf(float f) {
  union { float f; unsigned u; } v; v.f = f;
  unsigned r = v.u + 0x7fffu + ((v.u >> 16) & 1u);
  return (unsigned short)(r >> 16);
}

// truncating pack of two fp32 into [bf16(hi) | bf16(lo)] — single v_perm_b32.
// Truncation bias cancels in O = (P V)/(P 1) since denominator uses same P.
__device__ __forceinline__ unsigned pktr(float lo, float hi) {
  union { float f; unsigned u; } a, b; a.f = lo; b.f = hi;
  return __builtin_amdgcn_perm(b.u, a.u, 0x07060302u);
}

// async global->LDS DMA, 16B/lane. LDS dest = wave-uniform base + lane*16.
#define GLL(gp, lp) __builtin_amdgcn_global_load_lds(                      \
    (__attribute__((address_space(1))) void*)(gp),                         \
    (__attribute__((address_space(3))) void*)(lp), 16, 0, 0)

// ---------------------------------------------------------------------------
// Prep: X->bf16 | W->Wt bf16 transposed. (O-zero / L-zero passes removed —
// no atomics anymore, every output byte is fully written downstream.)
// ---------------------------------------------------------------------------
__global__ __launch_bounds__(256) void prep(
    const float* __restrict__ X,
    const float* __restrict__ Wq, const float* __restrict__ Wk, const float* __restrict__ Wv,
    unsigned short* __restrict__ Xb, unsigned short* __restrict__ Wt)
{
  const int b = blockIdx.x, tid = threadIdx.x;
  __shared__ unsigned short T[64][72];

  if (b < 3072) {                      // X fp32 -> bf16
    const int i = b * 256 + tid;
    const float4 v = ((const float4*)X)[i];
    ushort4 o;
    o.x = f2bf(v.x); o.y = f2bf(v.y); o.z = f2bf(v.z); o.w = f2bf(v.w);
    ((ushort4*)Xb)[i] = o;
  } else {                             // W [k][n] -> Wt [n][k] bf16, 64x64 tiles
    const int t = b - 3072;
    const int z = t / 144, rem = t % 144;
    const int k0 = (rem / 12) * 64, n0 = (rem % 12) * 64;
    const float* W = (z == 0) ? Wq : (z == 1) ? Wk : Wv;
    unsigned short* Od = Wt + (size_t)z * HID * HID;
    #pragma unroll
    for (int i = tid; i < 512; i += 256) {
      const int kr = i >> 3, c8 = (i & 7) * 8;
      const float4 a = *(const float4*)&W[(size_t)(k0 + kr) * HID + n0 + c8];
      const float4 bb = *(const float4*)&W[(size_t)(k0 + kr) * HID + n0 + c8 + 4];
      T[kr][c8 + 0] = f2bf(a.x);  T[kr][c8 + 1] = f2bf(a.y);
      T[kr][c8 + 2] = f2bf(a.z);  T[kr][c8 + 3] = f2bf(a.w);
      T[kr][c8 + 4] = f2bf(bb.x); T[kr][c8 + 5] = f2bf(bb.y);
      T[kr][c8 + 6] = f2bf(bb.z); T[kr][c8 + 7] = f2bf(bb.w);
    }
    __syncthreads();
    #pragma unroll
    for (int i = tid; i < 512; i += 256) {
      const int nr = i >> 3, c8 = (i & 7) * 8;
      ushort4 lo, hi;
      lo.x = T[c8 + 0][nr]; lo.y = T[c8 + 1][nr]; lo.z = T[c8 + 2][nr]; lo.w = T[c8 + 3][nr];
      hi.x = T[c8 + 4][nr]; hi.y = T[c8 + 5][nr]; hi.z = T[c8 + 6][nr]; hi.w = T[c8 + 7][nr];
      ushort4* dst = (ushort4*)&Od[(size_t)(n0 + nr) * HID + k0 + c8];
      dst[0] = lo; dst[1] = hi;
    }
  }
}

// ---------------------------------------------------------------------------
// Kernel 1: QKV projection (unchanged, known-good). 64x64 tile, BK=64,
// single-buffered 16 KB LDS, register prefetch, XOR-swizzled LDS,
// LDS-restaged coalesced epilogue. Q pre-scaled by 0.125*log2(e).
// V written [h][d][s_p] with key permutation matching attn's P A-fragments.
// ---------------------------------------------------------------------------
__global__ __launch_bounds__(256) void qkv_proj(
    const unsigned short* __restrict__ Xb, const unsigned short* __restrict__ Wt,
    const float* __restrict__ bq, const float* __restrict__ bk, const float* __restrict__ bv,
    unsigned short* __restrict__ Qo, unsigned short* __restrict__ Ko, unsigned short* __restrict__ Vo)
{
  const int z = blockIdx.z;
  const unsigned short* W = Wt + (size_t)z * HID * HID;   // [n][k]
  const float* bias = (z == 0) ? bq : (z == 1) ? bk : bv;
  unsigned short* Out = (z == 0) ? Qo : (z == 1) ? Ko : Vo;

  const int tid  = threadIdx.x;
  const int wave = tid >> 6;
  const int lane = tid & 63;
  const int g = lane >> 4, c = lane & 15;
  const int h  = blockIdx.x;
  const int n0 = h * 64;
  const int m0 = blockIdx.y * 64;

  __shared__ unsigned short Xl[4096];   // [m][k] swizzled
  __shared__ unsigned short Wl[4096];   // [n][k] swizzled

  const int r0 = tid >> 3, c80 = (tid & 7) * 8;
  const unsigned sOff0 = r0 * 64 + (c80 ^ ((r0 & 7) * 8));
  const unsigned sOff1 = (r0 + 32) * 64 + (c80 ^ ((r0 & 7) * 8));
  const unsigned short* xS0 = &Xb[(size_t)(m0 + r0) * HID + c80];
  const unsigned short* xS1 = &Xb[(size_t)(m0 + r0 + 32) * HID + c80];
  const unsigned short* wS0 = &W[(size_t)(n0 + r0) * HID + c80];
  const unsigned short* wS1 = &W[(size_t)(n0 + r0 + 32) * HID + c80];

  bf16x8 rx0 = *(const bf16x8*)xS0, rx1 = *(const bf16x8*)xS1;
  bf16x8 rw0 = *(const bf16x8*)wS0, rw1 = *(const bf16x8*)wS1;

  const int swz = (c & 7) * 8;
  unsigned aRi[2], bRi[8];
  aRi[0] = (wave * 16 + c) * 64 + ((g * 8) ^ swz);
  aRi[1] = (wave * 16 + c) * 64 + ((32 + g * 8) ^ swz);
  #pragma unroll
  for (int nt = 0; nt < 4; ++nt) {
    bRi[2 * nt]     = (nt * 16 + c) * 64 + ((g * 8) ^ swz);
    bRi[2 * nt + 1] = (nt * 16 + c) * 64 + ((32 + g * 8) ^ swz);
  }

  f32x4 acc[4] = {{0.f,0.f,0.f,0.f},{0.f,0.f,0.f,0.f},{0.f,0.f,0.f,0.f},{0.f,0.f,0.f,0.f}};

  for (int k0 = 0; k0 < HID; k0 += 64) {
    __syncthreads();
    *(bf16x8*)&Xl[sOff0] = rx0;
    *(bf16x8*)&Xl[sOff1] = rx1;
    *(bf16x8*)&Wl[sOff0] = rw0;
    *(bf16x8*)&Wl[sOff1] = rw1;
    __syncthreads();

    if (k0 + 64 < HID) {   // prefetch next k-slab (lands during MFMAs)
      xS0 += 64; xS1 += 64; wS0 += 64; wS1 += 64;
      rx0 = *(const bf16x8*)xS0; rx1 = *(const bf16x8*)xS1;
      rw0 = *(const bf16x8*)wS0; rw1 = *(const bf16x8*)wS1;
    }

    const bf16x8 a0 = *(const bf16x8*)&Xl[aRi[0]];
    const bf16x8 a1 = *(const bf16x8*)&Xl[aRi[1]];
    #pragma unroll
    for (int nt = 0; nt < 4; ++nt) {
      const bf16x8 b0 = *(const bf16x8*)&Wl[bRi[2 * nt]];
      const bf16x8 b1 = *(const bf16x8*)&Wl[bRi[2 * nt + 1]];
      acc[nt] = __builtin_amdgcn_mfma_f32_16x16x32_bf16(a0, b0, acc[nt], 0, 0, 0);
      acc[nt] = __builtin_amdgcn_mfma_f32_16x16x32_bf16(a1, b1, acc[nt], 0, 0, 0);
    }
  }

  // epilogue: restage through Xl (swizzled) -> coalesced b128 stores
  const float qsc = (z == 0) ? 0.1803368782f : 1.0f;   // 0.125 * log2(e)
  __syncthreads();
  #pragma unroll
  for (int nt = 0; nt < 4; ++nt) {
    const float bv_ = bias[n0 + nt * 16 + c];
    #pragma unroll
    for (int r = 0; r < 4; ++r) {
      const unsigned short val = f2bf((acc[nt][r] + bv_) * qsc);
      if (z == 2) {
        const int row = nt * 16 + c;
        const int col = (wave >> 1) * 32 + g * 8 + r + (wave & 1) * 4;
        Xl[row * 64 + (col ^ ((row & 7) * 8))] = val;
      } else {
        const int row = wave * 16 + 4 * g + r;
        const int col = nt * 16 + c;
        Xl[row * 64 + (col ^ ((row & 7) * 8))] = val;
      }
    }
  }
  __syncthreads();
  #pragma unroll
  for (int jj = 0; jj < 2; ++jj) {
    const int j = tid + 256 * jj, row = j >> 3, c8 = (j & 7) * 8;
    const bf16x8 v = *(const bf16x8*)&Xl[row * 64 + (c8 ^ ((row & 7) * 8))];
    if (z == 2)
      *(bf16x8*)&Out[((size_t)h * HD + row) * S_LEN + m0 + c8] = v;   // [h][d][s_p]
    else
      *(bf16x8*)&Out[((size_t)h * S_LEN + m0 + row) * HD + c8] = v;   // [h][s][d]
  }
}

// ---------------------------------------------------------------------------
// Kernel 2: attention. 4 waves x 32 q = 128 q/WG, KV-split 2 -> 768 WGs
// (exactly 3 WGs/CU, LDS cap is 5). Double-buffered K/V LDS, ONE barrier/iter.
// Staging now via global_load_lds (async DMA, no reg round-trip, no ds_write):
// LDS dest is linear (base + lane*16); the XOR bank-swizzle is applied to the
// GLOBAL source column instead (inverse == same involution), so the read-side
// kRi indices are unchanged:  LDS[r][x] = K[r][x ^ ((r&7)*8)].
// Epilogue: plain stores (NO atomics) — sp=0 partial to O, sp=1 to Op1,
// row-sum partials to Lp. reduce_norm merges.
// ---------------------------------------------------------------------------
__global__ __launch_bounds__(256, 4) void attn(
    const unsigned short* __restrict__ Q, const unsigned short* __restrict__ K,
    const unsigned short* __restrict__ Vp,   // [h][d][s_p]
    float* __restrict__ O, float* __restrict__ Op1, float* __restrict__ Lp)
{
  const int qt = blockIdx.x;   // 0..31
  const int h  = blockIdx.y;   // 0..11
  const int sp = blockIdx.z;   // 0..1
  const int tid  = threadIdx.x;
  const int wave = tid >> 6;
  const int lane = tid & 63;
  const int g = lane >> 4, c = lane & 15;
  const int q0 = qt * 128;
  const int k_base = sp * 2048;
  const int NIT = 32;

  __shared__ unsigned short KB[2][4096];   // [key][d] swizzled
  __shared__ unsigned short VB[2][4096];   // [d][key_p] swizzled

  // Q B-frags (loop-invariant, from global)
  bf16x8 aq[2][2];
  #pragma unroll
  for (int s = 0; s < 2; ++s) {
    const size_t qrow = (size_t)h * S_LEN + q0 + wave * 32 + s * 16 + c;
    aq[s][0] = *(const bf16x8*)&Q[qrow * HD + g * 8];
    aq[s][1] = *(const bf16x8*)&Q[qrow * HD + 32 + g * 8];
  }

  bf16x8 bones8;   // B column 0 = 1.0 -> C[:,0] = row sums
  {
    const unsigned short one_bf = (c == 0) ? 0x3F80u : 0u;
    #pragma unroll
    for (int j = 0; j < 8; ++j) ((unsigned short*)&bones8)[j] = one_bf;
  }

  const int swz = (c & 7) * 8;
  unsigned kRi[8];             // read offsets; identical pattern serves K and V
  #pragma unroll
  for (int mt = 0; mt < 4; ++mt) {
    kRi[2 * mt]     = (mt * 16 + c) * 64 + ((g * 8) ^ swz);
    kRi[2 * mt + 1] = (mt * 16 + c) * 64 + ((32 + g * 8) ^ swz);
  }

  // --- staging sources, pre-swizzled so linear LDS dest lands swizzled ---
  // wave w, issue i in {0,1}: LDS bytes (w*2+i)*1024 + lane*16
  //   -> row = (w*2+i)*8 + (lane>>3), col elems (lane&7)*8
  // source col block = (lane&7) ^ (lane>>3)  (involution)
  const int sr  = lane >> 3;                 // row-within-8-group = row&7
  const int scb = ((lane & 7) ^ sr) * 8;     // pre-swizzled column (elements)
  const unsigned short* kG0 = &K[((size_t)h * S_LEN + k_base + wave * 16 + sr) * HD + scb];
  const unsigned short* kG1 = kG0 + (size_t)8 * HD;
  const unsigned short* vG0 = &Vp[((size_t)h * HD + wave * 16 + sr) * S_LEN + k_base + scb];
  const unsigned short* vG1 = vG0 + (size_t)8 * S_LEN;

  // prologue: slab 0 into buffer 0 (drained by the vmcnt(0) at first barrier)
  GLL(kG0, &KB[0][(wave * 2 + 0) * 512]);
  GLL(kG1, &KB[0][(wave * 2 + 1) * 512]);
  GLL(vG0, &VB[0][(wave * 2 + 0) * 512]);
  GLL(vG1, &VB[0][(wave * 2 + 1) * 512]);
  kG0 += (size_t)64 * HD; kG1 += (size_t)64 * HD; vG0 += 64; vG1 += 64;

  f32x4 o[2][4];
  #pragma unroll
  for (int s = 0; s < 2; ++s)
    #pragma unroll
    for (int dt = 0; dt < 4; ++dt) o[s][dt] = (f32x4){0.f, 0.f, 0.f, 0.f};
  f32x4 lacc[2] = {{0.f,0.f,0.f,0.f},{0.f,0.f,0.f,0.f}};

  for (int kt = 0; kt < NIT; ++kt) {
    __syncthreads();                 // drains DMA into buf[cur]; frees buf[cur^1]
    const int cur = kt & 1;
    if (kt + 1 < NIT) {              // async-prefetch next slab into other buffer
      const int nxt = cur ^ 1;
      GLL(kG0, &KB[nxt][(wave * 2 + 0) * 512]);
      GLL(kG1, &KB[nxt][(wave * 2 + 1) * 512]);
      GLL(vG0, &VB[nxt][(wave * 2 + 0) * 512]);
      GLL(vG1, &VB[nxt][(wave * 2 + 1) * 512]);
      kG0 += (size_t)64 * HD; kG1 += (size_t)64 * HD; vG0 += 64; vG1 += 64;
    }
    const unsigned short* Kl = KB[cur];
    const unsigned short* Vt = VB[cur];

    // S^T = K Q^T per 16-key tile; exp2 + pack; concat pairs -> x32 A-frags
    bf16x8 apack[2][2];
    #pragma unroll
    for (int t = 0; t < 2; ++t) {
      const bf16x8 kf00 = *(const bf16x8*)&Kl[kRi[4 * t + 0]];
      const bf16x8 kf01 = *(const bf16x8*)&Kl[kRi[4 * t + 1]];
      const bf16x8 kf10 = *(const bf16x8*)&Kl[kRi[4 * t + 2]];
      const bf16x8 kf11 = *(const bf16x8*)&Kl[kRi[4 * t + 3]];
      #pragma unroll
      for (int s = 0; s < 2; ++s) {
        f32x4 sa = {0.f,0.f,0.f,0.f}, sb = {0.f,0.f,0.f,0.f};
        sa = __builtin_amdgcn_mfma_f32_16x16x32_bf16(kf00, aq[s][0], sa, 0, 0, 0);
        sa = __builtin_amdgcn_mfma_f32_16x16x32_bf16(kf01, aq[s][1], sa, 0, 0, 0);
        sb = __builtin_amdgcn_mfma_f32_16x16x32_bf16(kf10, aq[s][0], sb, 0, 0, 0);
        sb = __builtin_amdgcn_mfma_f32_16x16x32_bf16(kf11, aq[s][1], sb, 0, 0, 0);
        union { unsigned u[4]; bf16x8 v; } pk;
        pk.u[0] = pktr(__builtin_amdgcn_exp2f(sa[0]), __builtin_amdgcn_exp2f(sa[1]));
        pk.u[1] = pktr(__builtin_amdgcn_exp2f(sa[2]), __builtin_amdgcn_exp2f(sa[3]));
        pk.u[2] = pktr(__builtin_amdgcn_exp2f(sb[0]), __builtin_amdgcn_exp2f(sb[1]));
        pk.u[3] = pktr(__builtin_amdgcn_exp2f(sb[2]), __builtin_amdgcn_exp2f(sb[3]));
        apack[s][t] = pk.v;
      }
    }

    __builtin_amdgcn_s_setprio(1);   // favor the pure-MFMA cluster (T5)
    #pragma unroll
    for (int dt = 0; dt < 4; ++dt) {
      const bf16x8 vb0 = *(const bf16x8*)&Vt[kRi[2 * dt]];
      const bf16x8 vb1 = *(const bf16x8*)&Vt[kRi[2 * dt + 1]];
      #pragma unroll
      for (int s = 0; s < 2; ++s) {
        o[s][dt] = __builtin_amdgcn_mfma_f32_16x16x32_bf16(apack[s][0], vb0, o[s][dt], 0, 0, 0);
        o[s][dt] = __builtin_amdgcn_mfma_f32_16x16x32_bf16(apack[s][1], vb1, o[s][dt], 0, 0, 0);
      }
    }
    #pragma unroll
    for (int s = 0; s < 2; ++s) {
      lacc[s] = __builtin_amdgcn_mfma_f32_16x16x32_bf16(apack[s][0], bones8, lacc[s], 0, 0, 0);
      lacc[s] = __builtin_amdgcn_mfma_f32_16x16x32_bf16(apack[s][1], bones8, lacc[s], 0, 0, 0);
    }
    __builtin_amdgcn_s_setprio(0);
  }

  // epilogue: plain stores of partials (each element written exactly once)
  float* __restrict__ Od = (sp == 0) ? O : Op1;
  #pragma unroll
  for (int s = 0; s < 2; ++s) {
    #pragma unroll
    for (int dt = 0; dt < 4; ++dt) {
      #pragma unroll
      for (int r = 0; r < 4; ++r) {
        const int row = q0 + wave * 32 + s * 16 + 4 * g + r;
        Od[(size_t)row * HID + h * HD + dt * 16 + c] = o[s][dt][r];
      }
    }
  }
  if (c == 0) {
    #pragma unroll
    for (int s = 0; s < 2; ++s)
      #pragma unroll
      for (int r = 0; r < 4; ++r) {
        const int row = q0 + wave * 32 + s * 16 + 4 * g + r;
        Lp[((size_t)sp * NH + h) * S_LEN + row] = lacc[s][r];
      }
  }
}

// ---------------------------------------------------------------------------
// Kernel 3: merge the two KV-split partials and normalize by the softmax
// denominator. Pure-BW: reads O + Op1 + Lp, writes O.
// ---------------------------------------------------------------------------
__global__ __launch_bounds__(256) void reduce_norm(float* __restrict__ O,
                                                   const float* __restrict__ Op1,
                                                   const float* __restrict__ Lp)
{
  const int i = blockIdx.x * 256 + threadIdx.x;
  float4 a = ((const float4*)O)[i];
  const float4 b = ((const float4*)Op1)[i];
  const int idx4 = i * 4;
  const int row = idx4 / HID;
  const int h   = (idx4 % HID) >> 6;
  const float inv = 1.0f / (Lp[h * S_LEN + row] + Lp[(NH + h) * S_LEN + row]);
  float4 r;
  r.x = (a.x + b.x) * inv; r.y = (a.y + b.y) * inv;
  r.z = (a.z + b.z) * inv; r.w = (a.w + b.w) * inv;
  ((float4*)O)[i] = r;
}

// ---------------------------------------------------------------------------
extern "C" void kernel_launch(void* const* d_in, const int* in_sizes, int n_in,
                              void* d_out, int out_size, void* d_ws, size_t ws_size,
                              hipStream_t stream) {
  const float* X  = (const float*)d_in[0];
  const float* Wq = (const float*)d_in[1];
  const float* bq = (const float*)d_in[2];
  const float* Wk = (const float*)d_in[3];
  const float* bk = (const float*)d_in[4];
  const float* Wv = (const float*)d_in[5];
  const float* bv = (const float*)d_in[6];

  unsigned short* Xb = (unsigned short*)d_ws;
  unsigned short* Wt = Xb + (size_t)S_LEN * HID;
  unsigned short* Qb = Wt + (size_t)3 * HID * HID;
  unsigned short* Kb = Qb + (size_t)NH * S_LEN * HD;
  unsigned short* Vb = Kb + (size_t)NH * S_LEN * HD;
  float* Op1 = (float*)(Vb + (size_t)NH * S_LEN * HD);   // sp=1 partial (12.6 MB)
  float* Lp  = Op1 + (size_t)S_LEN * HID;                // [2][NH][S] row-sum partials
  float* O = (float*)d_out;

  prep<<<dim3(3504), 256, 0, stream>>>(X, Wq, Wk, Wv, Xb, Wt);
  qkv_proj<<<dim3(12, 64, 3), 256, 0, stream>>>(Xb, Wt, bq, bk, bv, Qb, Kb, Vb);
  attn<<<dim3(32, 12, 2), 256, 0, stream>>>(Qb, Kb, Vb, O, Op1, Lp);
  reduce_norm<<<dim3((S_LEN * HID / 4) / 256), 256, 0, stream>>>(O, Op1, Lp);
}